// Round 18
// baseline (534.723 us; speedup 1.0000x reference)
//
#include <hip/hip_runtime.h>

typedef __attribute__((ext_vector_type(8))) short short8;
typedef __attribute__((ext_vector_type(4))) float f32x4;
typedef unsigned short u16;

#define BB   128
#define SS   256
#define FIN  40
#define HH   64
#define DD   128
#define NHH  4
#define LL   2
#define NEGV (-1e9f)

__device__ __forceinline__ u16 f2b(float f) {
    unsigned u = __float_as_uint(f);
    return (u16)((u + 0x7FFFu + ((u >> 16) & 1u)) >> 16);
}
__device__ __forceinline__ float b2f(u16 u) {
    return __uint_as_float(((unsigned)u) << 16);
}

__device__ __forceinline__ void gl_lds16(const void* g, void* s) {
    __builtin_amdgcn_global_load_lds(
        (const __attribute__((address_space(1))) void*)g,
        (__attribute__((address_space(3))) void*)s, 16, 0, 0);
}

// ------------------------------------------------- xwt2 = concat(x,mask,delta) @ W_ih^T + b_ih
// LAYOUT for GRU v8: xwt2[pair P 0..63][t 0..255][gatecol 0..191][2 rows]  (float2, L-coalesced)
__global__ __launch_bounds__(192) void xw_kernel(const float* __restrict__ x,
                                                 const float* __restrict__ mask,
                                                 const float* __restrict__ delta,
                                                 const float* __restrict__ w_ih,
                                                 const float* __restrict__ b_ih,
                                                 float* __restrict__ xwt) {
    __shared__ float inp[16][120];
    __shared__ float wl[192][21];
    int group = blockIdx.x >> 8;     // 16-row batch group
    int t = blockIdx.x & 255;
    int tid = threadIdx.x;

    for (int idx = tid; idx < 16 * 120; idx += 192) {
        int r = idx / 120, k = idx % 120;
        size_t g = (size_t)(group * 16 + r) * 256 + t;
        float v;
        if (k < 40)      v = x[g * FIN + k];
        else if (k < 80) v = mask[g * FIN + (k - 40)];
        else             v = delta[g * FIN + (k - 80)];
        inp[r][k] = v;
    }

    float acc[16];
#pragma unroll
    for (int r = 0; r < 16; ++r) acc[r] = 0.f;

    for (int kt = 0; kt < 6; ++kt) {
        __syncthreads();
        for (int idx = tid; idx < 192 * 20; idx += 192) {
            int r = idx / 20, k = idx % 20;
            wl[r][k] = w_ih[(size_t)r * 120 + kt * 20 + k];
        }
        __syncthreads();
#pragma unroll
        for (int kk = 0; kk < 20; ++kk) {
            float w = wl[tid][kk];
            int kg = kt * 20 + kk;
#pragma unroll
            for (int r = 0; r < 16; ++r) acc[r] += w * inp[r][kg];
        }
    }
    float bias = b_ih[tid];
#pragma unroll
    for (int p = 0; p < 8; ++p) {
        float2 v = {acc[2 * p] + bias, acc[2 * p + 1] + bias};
        *(float2*)&xwt[(((size_t)(group * 8 + p) * 256 + t) * 192 + tid) * 2] = v;
    }
}

// ---------------------------------------------------------------- combined pre-kernel v8:
// blocks 0..15  : barrier-free wave-local GRU (4 independent waves/block, 2 batch rows/wave;
//                 zero LDS, zero barriers; h exchanged in-wave via ds_bpermute/shfl)
// blocks 16..595: fp32->bf16 weight convert   blocks 596..723: time mask
__device__ __forceinline__ float gru_gate(float xr, float xz, float xn,
                                          float ar, float az, float an, float hold) {
    float r  = 1.f / (1.f + __expf(-(xr + ar)));
    float zg = 1.f / (1.f + __expf(-(xz + az)));
    float nx = xn + r * an;
    float n  = 2.f / (1.f + __expf(-2.f * nx)) - 1.f;   // tanh
    return (1.f - zg) * n + zg * hold;
}

__global__ __launch_bounds__(256, 1) void pre_kernel(const float* __restrict__ w_hh,
                                                     const float* __restrict__ b_hh,
                                                     const float* __restrict__ xwt,
                                                     u16* __restrict__ hsb,
                                                     const float* __restrict__ dm_w,
                                                     const float* __restrict__ ip_w,
                                                     const float* __restrict__ op_w,
                                                     const float* __restrict__ l1_w,
                                                     const float* __restrict__ l2_w,
                                                     u16* __restrict__ o_dm, u16* __restrict__ o_ip,
                                                     u16* __restrict__ o_op, u16* __restrict__ o_l1,
                                                     u16* __restrict__ o_l2,
                                                     const float* __restrict__ mask,
                                                     float* __restrict__ tm) {
    int blk = blockIdx.x;
    int tid = threadIdx.x;

    if (blk >= 16) {
        if (blk < 596) {
            // ---- weight convert: 2048 elems per block
            int cb = blk - 16;
            const float* s; u16* d; int off;
            if      (cb < 4)   { s = dm_w; d = o_dm; off = cb; }
            else if (cb < 52)  { s = ip_w; d = o_ip; off = cb - 4; }
            else if (cb < 68)  { s = op_w; d = o_op; off = cb - 52; }
            else if (cb < 324) { s = l1_w; d = o_l1; off = cb - 68; }
            else               { s = l2_w; d = o_l2; off = cb - 324; }
            int i = (off * 256 + tid) * 8;
            float4 a = *(const float4*)&s[i];
            float4 b = *(const float4*)&s[i + 4];
            short8 o;
            o[0] = (short)f2b(a.x); o[1] = (short)f2b(a.y); o[2] = (short)f2b(a.z); o[3] = (short)f2b(a.w);
            o[4] = (short)f2b(b.x); o[5] = (short)f2b(b.y); o[6] = (short)f2b(b.z); o[7] = (short)f2b(b.w);
            *(short8*)&d[i] = o;
        } else {
            int row = (blk - 596) * 256 + tid;
            if (row < BB * SS) {
                const float* m = mask + (size_t)row * FIN;
                float s = 0.f;
                for (int f = 0; f < FIN; ++f) s += m[f];
                tm[row] = (s > 0.f) ? 1.f : 0.f;
            }
        }
        return;
    }

    // ---- GRU v8: wave-local, barrier-free
    int w = tid >> 6, lane = tid & 63;
    int hi = lane >> 4, fr = lane & 15;
    int P = blk * 4 + w;              // batch pair 0..63
    int b0 = P * 2;

    // per-(gate, N-tile) bias at col n*16+fr
    float bgn[3][4];
#pragma unroll
    for (int g = 0; g < 3; ++g)
#pragma unroll
        for (int n = 0; n < 4; ++n) bgn[g][n] = b_hh[g * 64 + n * 16 + fr];

    // W_hh B-fragments (loop-invariant, 96 VGPR): lane holds W[g*64+n*16+fr][ks*32+hi*8+q]
    short8 wf[3][4][2];
#pragma unroll
    for (int g = 0; g < 3; ++g)
#pragma unroll
        for (int n = 0; n < 4; ++n)
#pragma unroll
            for (int ks = 0; ks < 2; ++ks) {
                const float* p = w_hh + (size_t)(g * 64 + n * 16 + fr) * 64 + ks * 32 + hi * 8;
#pragma unroll
                for (int q = 0; q < 8; ++q) wf[g][n][ks][q] = (short)f2b(p[q]);
            }

    const float* xg = xwt + (size_t)P * (256 * 192 * 2);

    // depth-4 xw prefetch (px[u][g] = float2{row0,row1} for gate g, col=lane)
    float2 px[4][3];
#pragma unroll
    for (int u = 0; u < 4; ++u)
#pragma unroll
        for (int g = 0; g < 3; ++g)
            px[u][g] = *(const float2*)&xg[((size_t)u * 192 + g * 64 + lane) * 2];

    unsigned hp = 0;                  // packed bf16 {h[row0][lane], h[row1][lane]}
    float h0 = 0.f, h1 = 0.f;
    unsigned hs[8];

    for (int t = 0; t < SS; t += 8) {
#pragma unroll
        for (int u = 0; u < 8; ++u) {
            int tp = t + u + 4; tp = (tp < SS) ? tp : (SS - 1);
            float2 n0 = *(const float2*)&xg[((size_t)tp * 192 + lane) * 2];
            float2 n1 = *(const float2*)&xg[((size_t)tp * 192 + 64 + lane) * 2];
            float2 n2 = *(const float2*)&xg[((size_t)tp * 192 + 128 + lane) * 2];

            // A-frag from hp via in-wave crossbar: af[ks][q] = h[fr-row][ks*32+hi*8+q]
            short8 af0, af1;
#pragma unroll
            for (int q = 0; q < 8; ++q) {
                int v0 = __builtin_amdgcn_ds_bpermute((hi * 8 + q) << 2, (int)hp);
                int v1 = __builtin_amdgcn_ds_bpermute((32 + hi * 8 + q) << 2, (int)hp);
                af0[q] = (short)((fr & 1) ? ((unsigned)v0 >> 16) : ((unsigned)v0 & 0xffffu));
                af1[q] = (short)((fr & 1) ? ((unsigned)v1 >> 16) : ((unsigned)v1 & 0xffffu));
            }

            f32x4 acc[3][4];
#pragma unroll
            for (int g = 0; g < 3; ++g)
#pragma unroll
                for (int n = 0; n < 4; ++n) {
                    acc[g][n] = (f32x4){bgn[g][n], bgn[g][n], bgn[g][n], bgn[g][n]};
                    acc[g][n] = __builtin_amdgcn_mfma_f32_16x16x32_bf16(af0, wf[g][n][0], acc[g][n], 0, 0, 0);
                    acc[g][n] = __builtin_amdgcn_mfma_f32_16x16x32_bf16(af1, wf[g][n][1], acc[g][n], 0, 0, 0);
                }

            // gather gh[g][r] for this lane's col (=lane): source lane = lane&15 (hi=0 holder),
            // register select n = lane>>4
            float gh[3][2];
#pragma unroll
            for (int g = 0; g < 3; ++g)
#pragma unroll
                for (int r = 0; r < 2; ++r) {
                    float t0 = __shfl(acc[g][0][r], fr);
                    float t1 = __shfl(acc[g][1][r], fr);
                    float t2 = __shfl(acc[g][2][r], fr);
                    float t3 = __shfl(acc[g][3][r], fr);
                    gh[g][r] = (hi == 0) ? t0 : (hi == 1) ? t1 : (hi == 2) ? t2 : t3;
                }

            float2 xr2 = px[u & 3][0], xz2 = px[u & 3][1], xn2 = px[u & 3][2];
            h0 = gru_gate(xr2.x, xz2.x, xn2.x, gh[0][0], gh[1][0], gh[2][0], h0);
            h1 = gru_gate(xr2.y, xz2.y, xn2.y, gh[0][1], gh[1][1], gh[2][1], h1);
            hp = (unsigned)f2b(h0) | ((unsigned)f2b(h1) << 16);
            hs[u] = hp;

            px[u & 3][0] = n0; px[u & 3][1] = n1; px[u & 3][2] = n2;
        }
        // flush 8 steps (coalesced 128B stores, fire-and-forget)
#pragma unroll
        for (int ts = 0; ts < 8; ++ts) {
            hsb[((size_t)b0 * SS + t + ts) * 64 + lane]       = (u16)(hs[ts] & 0xffffu);
            hsb[((size_t)(b0 + 1) * SS + t + ts) * 64 + lane] = (u16)(hs[ts] >> 16);
        }
    }
}

// ---------------------------------------------------------------- fused dm + qkv(layer 0)  (unchanged R17)
__global__ __launch_bounds__(256, 1) void dmqkv_kernel(const u16* __restrict__ hsb,
                                                       const u16* __restrict__ dmw,
                                                       const float* __restrict__ dmb,
                                                       const u16* __restrict__ ipw,
                                                       const float* __restrict__ ipb,
                                                       float* __restrict__ z,
                                                       u16* __restrict__ qkvb) {
    __shared__ __align__(16) u16 ZB[2][128 * 64];
    __shared__ __align__(16) u16 W1C[2][128 * 64];
    int bm = blockIdx.x;
    int tid = threadIdx.x;
    int w = tid >> 6, lane = tid & 63;
    int wrow = (w >> 1) * 64, wcol = (w & 1) * 64;
    int fr = lane & 15, hi = lane >> 4;
    int rl = lane >> 3, ssl = (lane & 7) ^ rl;
    int swz = fr & 7;

#pragma unroll
    for (int i = 0; i < 4; ++i) {
        int ch = w * 4 + i, row = ch * 8 + rl;
        gl_lds16(hsb + ((size_t)(bm * 128 + row)) * 64 + ssl * 8, &ZB[0][ch * 512]);
        gl_lds16(dmw + ((size_t)row) * 64 + ssl * 8, &W1C[0][ch * 512]);
    }
    __syncthreads();

    f32x4 acc[4][4];
#pragma unroll
    for (int m = 0; m < 4; ++m)
#pragma unroll
        for (int n = 0; n < 4; ++n) acc[m][n] = (f32x4){0.f, 0.f, 0.f, 0.f};
#pragma unroll
    for (int kk = 0; kk < 2; ++kk) {
        int soff = (((kk << 2) + hi) ^ swz) << 3;
        short8 a[4], b[4];
#pragma unroll
        for (int m = 0; m < 4; ++m)
            a[m] = *(const short8*)&ZB[0][(wrow + m * 16 + fr) * 64 + soff];
#pragma unroll
        for (int n = 0; n < 4; ++n)
            b[n] = *(const short8*)&W1C[0][(wcol + n * 16 + fr) * 64 + soff];
#pragma unroll
        for (int m = 0; m < 4; ++m)
#pragma unroll
            for (int n = 0; n < 4; ++n)
                acc[m][n] = __builtin_amdgcn_mfma_f32_16x16x32_bf16(a[m], b[n], acc[m][n], 0, 0, 0);
    }
    __syncthreads();

    float bv[4];
#pragma unroll
    for (int n = 0; n < 4; ++n) bv[n] = dmb[wcol + n * 16 + fr];
#pragma unroll
    for (int m = 0; m < 4; ++m)
#pragma unroll
        for (int j = 0; j < 4; ++j) {
            int lrow = wrow + m * 16 + hi * 4 + j;
            int row = bm * 128 + lrow;
#pragma unroll
            for (int n = 0; n < 4; ++n) {
                int col = wcol + n * 16 + fr;
                float o = acc[m][n][j] + bv[n];
                z[(size_t)row * 128 + col] = o;
                int e = col & 63;
                ZB[col >> 6][lrow * 64 + ((((e >> 3) ^ (lrow & 7))) << 3) + (e & 7)] = f2b(o);
            }
        }
    __syncthreads();

    for (int bn = 0; bn < 3; ++bn) {
#pragma unroll
        for (int hk = 0; hk < 2; ++hk)
#pragma unroll
            for (int i = 0; i < 4; ++i) {
                int ch = w * 4 + i, row = ch * 8 + rl;
                gl_lds16(ipw + ((size_t)(bn * 128 + row)) * 128 + hk * 64 + ssl * 8, &W1C[hk][ch * 512]);
            }
        __syncthreads();

        f32x4 aq[4][4];
#pragma unroll
        for (int m = 0; m < 4; ++m)
#pragma unroll
            for (int n = 0; n < 4; ++n) aq[m][n] = (f32x4){0.f, 0.f, 0.f, 0.f};
#pragma unroll
        for (int ks = 0; ks < 4; ++ks) {
            int hk = ks >> 1;
            int soff = ((((ks & 1) << 2) + hi) ^ swz) << 3;
            short8 a[4], b[4];
#pragma unroll
            for (int m = 0; m < 4; ++m)
                a[m] = *(const short8*)&ZB[hk][(wrow + m * 16 + fr) * 64 + soff];
#pragma unroll
            for (int n = 0; n < 4; ++n)
                b[n] = *(const short8*)&W1C[hk][(wcol + n * 16 + fr) * 64 + soff];
#pragma unroll
            for (int m = 0; m < 4; ++m)
#pragma unroll
                for (int n = 0; n < 4; ++n)
                    aq[m][n] = __builtin_amdgcn_mfma_f32_16x16x32_bf16(a[m], b[n], aq[m][n], 0, 0, 0);
        }
        float qb[4];
#pragma unroll
        for (int n = 0; n < 4; ++n) qb[n] = ipb[bn * 128 + wcol + n * 16 + fr];
#pragma unroll
        for (int m = 0; m < 4; ++m)
#pragma unroll
            for (int j = 0; j < 4; ++j) {
                int row = bm * 128 + wrow + m * 16 + hi * 4 + j;
#pragma unroll
                for (int n = 0; n < 4; ++n)
                    qkvb[(size_t)row * 384 + bn * 128 + wcol + n * 16 + fr] = f2b(aq[m][n][j] + qb[n]);
            }
        __syncthreads();
    }
}

// ---------------------------------------------------------------- fused layer tail (+ next-layer qkv) (unchanged R17)
template <bool DO_QKV>
__global__ __launch_bounds__(256, 1) void tailqkv_kernel(const u16* __restrict__ attnob,
                                                         const u16* __restrict__ opw,
                                                         const float* __restrict__ opb,
                                                         const float* __restrict__ ln1s,
                                                         const float* __restrict__ ln1b,
                                                         const u16* __restrict__ w1,
                                                         const float* __restrict__ b1,
                                                         const u16* __restrict__ w2,
                                                         const float* __restrict__ b2,
                                                         const float* __restrict__ lns,
                                                         const float* __restrict__ lnb,
                                                         const u16* __restrict__ ipw,
                                                         const float* __restrict__ ipb,
                                                         float* __restrict__ z,
                                                         u16* __restrict__ qkvb) {
    __shared__ __align__(16) u16 ZB[2][128 * 64];
    __shared__ __align__(16) u16 W1C[2][128 * 64];
    __shared__ __align__(16) u16 W2C[2][128 * 64];
    __shared__ __align__(16) u16 A1[2][128 * 64];
    __shared__ float lred[2][2][128];
    int bm = blockIdx.x;
    int tid = threadIdx.x;
    int w = tid >> 6, lane = tid & 63;
    int wrow = (w >> 1) * 64, wcol = (w & 1) * 64;
    int fr = lane & 15, hi = lane >> 4;
    int rl = lane >> 3, ssl = (lane & 7) ^ rl;
    int swz = fr & 7;
    int xh = wrow >> 6;

#pragma unroll
    for (int hk = 0; hk < 2; ++hk)
#pragma unroll
        for (int i = 0; i < 4; ++i) {
            int ch = w * 4 + i, row = ch * 8 + rl;
            gl_lds16(attnob + ((size_t)(bm * 128 + row)) * 128 + hk * 64 + ssl * 8, &ZB[hk][ch * 512]);
            gl_lds16(opw + ((size_t)row) * 128 + hk * 64 + ssl * 8, &W1C[hk][ch * 512]);
        }
    __syncthreads();

    {
        f32x4 acc1[4][4];
#pragma unroll
        for (int m = 0; m < 4; ++m)
#pragma unroll
            for (int n = 0; n < 4; ++n) acc1[m][n] = (f32x4){0.f, 0.f, 0.f, 0.f};
#pragma unroll
        for (int ks = 0; ks < 4; ++ks) {
            int hk = ks >> 1;
            int soff = ((((ks & 1) << 2) + hi) ^ swz) << 3;
            short8 a[4], b[4];
#pragma unroll
            for (int m = 0; m < 4; ++m)
                a[m] = *(const short8*)&ZB[hk][(wrow + m * 16 + fr) * 64 + soff];
#pragma unroll
            for (int n = 0; n < 4; ++n)
                b[n] = *(const short8*)&W1C[hk][(wcol + n * 16 + fr) * 64 + soff];
#pragma unroll
            for (int m = 0; m < 4; ++m)
#pragma unroll
                for (int n = 0; n < 4; ++n)
                    acc1[m][n] = __builtin_amdgcn_mfma_f32_16x16x32_bf16(a[m], b[n], acc1[m][n], 0, 0, 0);
        }

        float bv[4];
#pragma unroll
        for (int n = 0; n < 4; ++n) bv[n] = opb[wcol + n * 16 + fr];
        float v[4][4][4];
#pragma unroll
        for (int m = 0; m < 4; ++m)
#pragma unroll
            for (int j = 0; j < 4; ++j) {
                int row = bm * 128 + wrow + m * 16 + hi * 4 + j;
#pragma unroll
                for (int n = 0; n < 4; ++n)
                    v[m][n][j] = acc1[m][n][j] + bv[n] + z[(size_t)row * 128 + wcol + n * 16 + fr];
            }
#pragma unroll
        for (int m = 0; m < 4; ++m)
#pragma unroll
            for (int j = 0; j < 4; ++j) {
                float s = v[m][0][j] + v[m][1][j] + v[m][2][j] + v[m][3][j];
                float q = v[m][0][j]*v[m][0][j] + v[m][1][j]*v[m][1][j]
                        + v[m][2][j]*v[m][2][j] + v[m][3][j]*v[m][3][j];
#pragma unroll
                for (int off = 1; off <= 8; off <<= 1) {
                    s += __shfl_xor(s, off);
                    q += __shfl_xor(q, off);
                }
                if (fr == 0) {
                    int lrow = wrow + m * 16 + hi * 4 + j;
                    lred[0][w & 1][lrow] = s;
                    lred[1][w & 1][lrow] = q;
                }
            }
        __syncthreads();
        float sv[4], bb[4];
#pragma unroll
        for (int n = 0; n < 4; ++n) {
            sv[n] = ln1s[wcol + n * 16 + fr];
            bb[n] = ln1b[wcol + n * 16 + fr];
        }
#pragma unroll
        for (int m = 0; m < 4; ++m)
#pragma unroll
            for (int j = 0; j < 4; ++j) {
                int lrow = wrow + m * 16 + hi * 4 + j;
                float mean = (lred[0][0][lrow] + lred[0][1][lrow]) * (1.f / 128.f);
                float msq  = (lred[1][0][lrow] + lred[1][1][lrow]) * (1.f / 128.f);
                float rstd = rsqrtf(msq - mean * mean + 1e-5f);
                int row = bm * 128 + lrow;
#pragma unroll
                for (int n = 0; n < 4; ++n) {
                    int col = wcol + n * 16 + fr;
                    float o = (v[m][n][j] - mean) * rstd * sv[n] + bb[n];
                    z[(size_t)row * 128 + col] = o;
                    int e = col & 63;
                    ZB[col >> 6][lrow * 64 + ((((e >> 3) ^ (lrow & 7))) << 3) + (e & 7)] = f2b(o);
                }
            }
    }
    __syncthreads();

    f32x4 acc2[4][4];
#pragma unroll
    for (int m = 0; m < 4; ++m)
#pragma unroll
        for (int n = 0; n < 4; ++n) acc2[m][n] = (f32x4){0.f, 0.f, 0.f, 0.f};

    for (int ci = 0; ci < 16; ++ci) {
#pragma unroll
        for (int hk = 0; hk < 2; ++hk)
#pragma unroll
            for (int i = 0; i < 4; ++i) {
                int ch = w * 4 + i, row = ch * 8 + rl;
                gl_lds16(w1 + ((size_t)(ci * 128 + row)) * 128 + hk * 64 + ssl * 8, &W1C[hk][ch * 512]);
                gl_lds16(w2 + ((size_t)row) * 2048 + ci * 128 + hk * 64 + ssl * 8, &W2C[hk][ch * 512]);
            }
        __syncthreads();

        f32x4 acc1[4][4];
#pragma unroll
        for (int m = 0; m < 4; ++m)
#pragma unroll
            for (int n = 0; n < 4; ++n) acc1[m][n] = (f32x4){0.f, 0.f, 0.f, 0.f};
#pragma unroll
        for (int ks = 0; ks < 4; ++ks) {
            int hk = ks >> 1;
            int soff = ((((ks & 1) << 2) + hi) ^ swz) << 3;
            short8 a[4], b[4];
#pragma unroll
            for (int m = 0; m < 4; ++m)
                a[m] = *(const short8*)&W1C[hk][(wrow + m * 16 + fr) * 64 + soff];
#pragma unroll
            for (int n = 0; n < 4; ++n)
                b[n] = *(const short8*)&ZB[hk][(wcol + n * 16 + fr) * 64 + soff];
#pragma unroll
            for (int m = 0; m < 4; ++m)
#pragma unroll
                for (int n = 0; n < 4; ++n)
                    acc1[m][n] = __builtin_amdgcn_mfma_f32_16x16x32_bf16(a[m], b[n], acc1[m][n], 0, 0, 0);
        }
#pragma unroll
        for (int m = 0; m < 4; ++m) {
            int x0 = wrow + m * 16 + hi * 4;
            float4 bb = *(const float4*)&b1[ci * 128 + x0];
            int slot = (x0 & 63) >> 3;
            int wadd = x0 & 7;
#pragma unroll
            for (int n = 0; n < 4; ++n) {
                int r = wcol + n * 16 + fr;
                float v0 = fmaxf(acc1[m][n][0] + bb.x, 0.f);
                float v1 = fmaxf(acc1[m][n][1] + bb.y, 0.f);
                float v2 = fmaxf(acc1[m][n][2] + bb.z, 0.f);
                float v3 = fmaxf(acc1[m][n][3] + bb.w, 0.f);
                uint2 pk;
                pk.x = (unsigned)f2b(v0) | ((unsigned)f2b(v1) << 16);
                pk.y = (unsigned)f2b(v2) | ((unsigned)f2b(v3) << 16);
                *(uint2*)&A1[xh][r * 64 + ((slot ^ (r & 7)) << 3) + wadd] = pk;
            }
        }
        __syncthreads();

#pragma unroll
        for (int ks = 0; ks < 4; ++ks) {
            int hk = ks >> 1;
            int soff = ((((ks & 1) << 2) + hi) ^ swz) << 3;
            short8 a[4], b[4];
#pragma unroll
            for (int m = 0; m < 4; ++m)
                a[m] = *(const short8*)&W2C[hk][(wrow + m * 16 + fr) * 64 + soff];
#pragma unroll
            for (int n = 0; n < 4; ++n)
                b[n] = *(const short8*)&A1[hk][(wcol + n * 16 + fr) * 64 + soff];
#pragma unroll
            for (int m = 0; m < 4; ++m)
#pragma unroll
                for (int n = 0; n < 4; ++n)
                    acc2[m][n] = __builtin_amdgcn_mfma_f32_16x16x32_bf16(a[m], b[n], acc2[m][n], 0, 0, 0);
        }
        __syncthreads();
    }

    float vv[4][4][4];
#pragma unroll
    for (int m = 0; m < 4; ++m) {
        int x0 = wrow + m * 16 + hi * 4;
        float4 bb = *(const float4*)&b2[x0];
#pragma unroll
        for (int n = 0; n < 4; ++n) {
            int y = wcol + n * 16 + fr;
            float4 zo = *(const float4*)&z[((size_t)(bm * 128 + y)) * 128 + x0];
            vv[m][n][0] = acc2[m][n][0] + bb.x + zo.x;
            vv[m][n][1] = acc2[m][n][1] + bb.y + zo.y;
            vv[m][n][2] = acc2[m][n][2] + bb.z + zo.z;
            vv[m][n][3] = acc2[m][n][3] + bb.w + zo.w;
        }
    }
#pragma unroll
    for (int n = 0; n < 4; ++n) {
        float s = 0.f, q = 0.f;
#pragma unroll
        for (int m = 0; m < 4; ++m)
#pragma unroll
            for (int j = 0; j < 4; ++j) { float v = vv[m][n][j]; s += v; q += v * v; }
        s += __shfl_xor(s, 16); s += __shfl_xor(s, 32);
        q += __shfl_xor(q, 16); q += __shfl_xor(q, 32);
        if (hi == 0) {
            int y = wcol + n * 16 + fr;
            lred[0][xh][y] = s;
            lred[1][xh][y] = q;
        }
    }
    __syncthreads();
#pragma unroll
    for (int n = 0; n < 4; ++n) {
        int y = wcol + n * 16 + fr;
        float mean = (lred[0][0][y] + lred[0][1][y]) * (1.f / 128.f);
        float msq  = (lred[1][0][y] + lred[1][1][y]) * (1.f / 128.f);
        float rstd = rsqrtf(msq - mean * mean + 1e-5f);
#pragma unroll
        for (int m = 0; m < 4; ++m) {
            int x0 = wrow + m * 16 + hi * 4;
            float4 sv = *(const float4*)&lns[x0];
            float4 bv = *(const float4*)&lnb[x0];
            float o0 = (vv[m][n][0] - mean) * rstd * sv.x + bv.x;
            float o1 = (vv[m][n][1] - mean) * rstd * sv.y + bv.y;
            float o2 = (vv[m][n][2] - mean) * rstd * sv.z + bv.z;
            float o3 = (vv[m][n][3] - mean) * rstd * sv.w + bv.w;
            size_t zoff = ((size_t)(bm * 128 + y)) * 128 + x0;
            *(float4*)&z[zoff] = (float4){o0, o1, o2, o3};
            if (DO_QKV) {
#pragma unroll
                for (int j = 0; j < 4; ++j) {
                    int col = x0 + j;
                    int e = col & 63;
                    float ov = (j == 0) ? o0 : (j == 1) ? o1 : (j == 2) ? o2 : o3;
                    ZB[col >> 6][y * 64 + ((((e >> 3) ^ (y & 7))) << 3) + (e & 7)] = f2b(ov);
                }
            }
        }
    }

    if (DO_QKV) {
        __syncthreads();
        for (int bn = 0; bn < 3; ++bn) {
#pragma unroll
            for (int hk = 0; hk < 2; ++hk)
#pragma unroll
                for (int i = 0; i < 4; ++i) {
                    int ch = w * 4 + i, row = ch * 8 + rl;
                    gl_lds16(ipw + ((size_t)(bn * 128 + row)) * 128 + hk * 64 + ssl * 8, &W1C[hk][ch * 512]);
                }
            __syncthreads();

            f32x4 aq[4][4];
#pragma unroll
            for (int m = 0; m < 4; ++m)
#pragma unroll
                for (int n = 0; n < 4; ++n) aq[m][n] = (f32x4){0.f, 0.f, 0.f, 0.f};
#pragma unroll
            for (int ks = 0; ks < 4; ++ks) {
                int hk = ks >> 1;
                int soff = ((((ks & 1) << 2) + hi) ^ swz) << 3;
                short8 a[4], b[4];
#pragma unroll
                for (int m = 0; m < 4; ++m)
                    a[m] = *(const short8*)&ZB[hk][(wrow + m * 16 + fr) * 64 + soff];
#pragma unroll
                for (int n = 0; n < 4; ++n)
                    b[n] = *(const short8*)&W1C[hk][(wcol + n * 16 + fr) * 64 + soff];
#pragma unroll
                for (int m = 0; m < 4; ++m)
#pragma unroll
                    for (int n = 0; n < 4; ++n)
                        aq[m][n] = __builtin_amdgcn_mfma_f32_16x16x32_bf16(a[m], b[n], aq[m][n], 0, 0, 0);
            }
            float qb[4];
#pragma unroll
            for (int n = 0; n < 4; ++n) qb[n] = ipb[bn * 128 + wcol + n * 16 + fr];
#pragma unroll
            for (int m = 0; m < 4; ++m)
#pragma unroll
                for (int j = 0; j < 4; ++j) {
                    int row = bm * 128 + wrow + m * 16 + hi * 4 + j;
#pragma unroll
                    for (int n = 0; n < 4; ++n)
                        qkvb[(size_t)row * 384 + bn * 128 + wcol + n * 16 + fr] = f2b(aq[m][n][j] + qb[n]);
                }
            __syncthreads();
        }
    }
}

// ---------------------------------------------------------------- MFMA attention (unchanged)
__global__ __launch_bounds__(256) void attn_mfma_kernel(const u16* __restrict__ qkv,
                                                        const float* __restrict__ tm,
                                                        u16* __restrict__ attno) {
    __shared__ __align__(16) u16 Kl[256 * 40];
    __shared__ __align__(16) u16 Vt[32 * 264];
    __shared__ __align__(16) u16 Pl[4][64 * 72];
    __shared__ float tmb[256];
    int bh = blockIdx.x;
    int b = bh >> 2, hd = bh & 3;
    int tid = threadIdx.x;
    int w = tid >> 6, lane = tid & 63;
    int fr = lane & 15, hi = lane >> 4;
    const u16* base = qkv + (size_t)b * SS * 384 + hd * 32;

    for (int idx = tid; idx < 1024; idx += 256) {
        int r = idx >> 2, s = idx & 3;
        short8 v = *(const short8*)(base + (size_t)r * 384 + 128 + s * 8);
        *(short8*)&Kl[r * 40 + s * 8] = v;
    }
    for (int idx = tid; idx < 1024; idx += 256) {
        int r = idx >> 2, s = idx & 3;
        short8 v = *(const short8*)(base + (size_t)r * 384 + 256 + s * 8);
#pragma unroll
        for (int q = 0; q < 8; ++q) Vt[(s * 8 + q) * 264 + r] = (u16)v[q];
    }
    tmb[tid] = (tm[b * SS + tid] > 0.f) ? 0.f : NEGV;

    int q0 = w * 64;
    short8 qf[4];
#pragma unroll
    for (int m = 0; m < 4; ++m)
        qf[m] = *(const short8*)(base + (size_t)(q0 + m * 16 + fr) * 384 + hi * 8);
    __syncthreads();

    const float scale = 0.17677669529663687f;
    f32x4 accO[4][2];
#pragma unroll
    for (int m = 0; m < 4; ++m) {
        accO[m][0] = (f32x4){0.f, 0.f, 0.f, 0.f};
        accO[m][1] = (f32x4){0.f, 0.f, 0.f, 0.f};
    }
    float den[4][4];
#pragma unroll
    for (int m = 0; m < 4; ++m)
#pragma unroll
        for (int j = 0; j < 4; ++j) den[m][j] = 0.f;

    u16* pw = &Pl[w][0];

    for (int kt = 0; kt < 4; ++kt) {
        f32x4 accS[4][4];
#pragma unroll
        for (int m = 0; m < 4; ++m)
#pragma unroll
            for (int n = 0; n < 4; ++n) accS[m][n] = (f32x4){0.f, 0.f, 0.f, 0.f};
        short8 kf[4];
#pragma unroll
        for (int n = 0; n < 4; ++n)
            kf[n] = *(const short8*)&Kl[(kt * 64 + n * 16 + fr) * 40 + hi * 8];
#pragma unroll
        for (int m = 0; m < 4; ++m)
#pragma unroll
            for (int n = 0; n < 4; ++n)
                accS[m][n] = __builtin_amdgcn_mfma_f32_16x16x32_bf16(qf[m], kf[n], accS[m][n], 0, 0, 0);

        float bias[4];
#pragma unroll
        for (int n = 0; n < 4; ++n) bias[n] = tmb[kt * 64 + n * 16 + fr];

#pragma unroll
        for (int m = 0; m < 4; ++m) {
            float rs0 = 0.f, rs1 = 0.f, rs2 = 0.f, rs3 = 0.f;
#pragma unroll
            for (int n = 0; n < 4; ++n) {
                float p0 = __expf(accS[m][n][0] * scale + bias[n]);
                float p1 = __expf(accS[m][n][1] * scale + bias[n]);
                float p2 = __expf(accS[m][n][2] * scale + bias[n]);
                float p3 = __expf(accS[m][n][3] * scale + bias[n]);
                rs0 += p0; rs1 += p1; rs2 += p2; rs3 += p3;
                int cb = n * 16 + fr;
                pw[(m * 16 + hi * 4 + 0) * 72 + cb] = f2b(p0);
                pw[(m * 16 + hi * 4 + 1) * 72 + cb] = f2b(p1);
                pw[(m * 16 + hi * 4 + 2) * 72 + cb] = f2b(p2);
                pw[(m * 16 + hi * 4 + 3) * 72 + cb] = f2b(p3);
            }
#pragma unroll
            for (int off = 1; off <= 8; off <<= 1) {
                rs0 += __shfl_xor(rs0, off);
                rs1 += __shfl_xor(rs1, off);
                rs2 += __shfl_xor(rs2, off);
                rs3 += __shfl_xor(rs3, off);
            }
            den[m][0] += rs0; den[m][1] += rs1; den[m][2] += rs2; den[m][3] += rs3;
        }
        asm volatile("s_waitcnt lgkmcnt(0)" ::: "memory");

#pragma unroll
        for (int ks = 0; ks < 2; ++ks) {
            short8 pf[4], vf[2];
#pragma unroll
            for (int m = 0; m < 4; ++m)
                pf[m] = *(const short8*)&pw[(m * 16 + fr) * 72 + ks * 32 + hi * 8];
#pragma unroll
            for (int nd = 0; nd < 2; ++nd)
                vf[nd] = *(const short8*)&Vt[(nd * 16 + fr) * 264 + kt * 64 + ks * 32 + hi * 8];
#pragma unroll
            for (int m = 0; m < 4; ++m)
#pragma unroll
                for (int nd = 0; nd < 2; ++nd)
                    accO[m][nd] = __builtin_amdgcn_mfma_f32_16x16x32_bf16(pf[m], vf[nd], accO[m][nd], 0, 0, 0);
        }
    }

    u16* orow = attno + (size_t)(b * SS + q0) * DD + hd * 32;
#pragma unroll
    for (int m = 0; m < 4; ++m)
#pragma unroll
        for (int j = 0; j < 4; ++j) {
            float inv = 1.f / den[m][j];
            int qr = m * 16 + hi * 4 + j;
            orow[(size_t)qr * DD + fr]      = f2b(accO[m][0][j] * inv);
            orow[(size_t)qr * DD + 16 + fr] = f2b(accO[m][1][j] * inv);
        }
}

// ---------------------------------------------------------------- fused score + softmax-pool + routed heads
__global__ __launch_bounds__(256) void pool_all_kernel(const float* __restrict__ z,
                                                       const float* __restrict__ score_w,
                                                       const float* __restrict__ score_b,
                                                       const float* __restrict__ tm,
                                                       const float* __restrict__ reg_w,
                                                       const float* __restrict__ reg_b,
                                                       const float* __restrict__ bin_w,
                                                       const float* __restrict__ bin_b,
                                                       const int* __restrict__ wid,
                                                       float* __restrict__ out) {
    int b = blockIdx.x;
    int tid = threadIdx.x;
    __shared__ float sw[128];
    __shared__ float al[SS];
    __shared__ float red[8];
    __shared__ float pp[2][128];
    __shared__ float p[128];

    if (tid < 128) sw[tid] = score_w[tid];
    __syncthreads();

    const float* zr = z + ((size_t)b * SS + tid) * DD;
    float acc = 0.f;
#pragma unroll
    for (int j = 0; j < 128; j += 4) {
        float4 a = *(const float4*)&zr[j];
        float4 wv = *(const float4*)&sw[j];
        acc += a.x * wv.x + a.y * wv.y + a.z * wv.z + a.w * wv.w;
    }
    float sc = acc + score_b[0];
    sc = (tm[b * SS + tid] > 0.f) ? sc : NEGV;

    float m = sc;
#pragma unroll
    for (int off = 32; off; off >>= 1) m = fmaxf(m, __shfl_xor(m, off));
    if ((tid & 63) == 0) red[tid >> 6] = m;
    __syncthreads();
    m = fmaxf(fmaxf(red[0], red[1]), fmaxf(red[2], red[3]));
    float e = __expf(sc - m);
    float ssum = e;
#pragma unroll
    for (int off = 32; off; off >>= 1) ssum += __shfl_xor(ssum, off);
    if ((tid & 63) == 0) red[4 + (tid >> 6)] = ssum;
    __syncthreads();
    ssum = red[4] + red[5] + red[6] + red[7];
    al[tid] = e / ssum;
    __syncthreads();

    int d = tid & 127, half = tid >> 7;
    float pa = 0.f;
    for (int t = half; t < SS; t += 2) pa += al[t] * z[((size_t)b * SS + t) * DD + d];
    pp[half][d] = pa;
    __syncthreads();
    if (tid < 128) p[tid] = pp[0][tid] + pp[1][tid];
    __syncthreads();

    if (tid < 9) {
        int wi = wid[b];
        const float* wrow;
        float bias;
        if (tid < 8) { wrow = reg_w + ((size_t)wi * 8 + tid) * 128; bias = reg_b[wi * 8 + tid]; }
        else         { wrow = bin_w + (size_t)wi * 128;             bias = bin_b[wi]; }
        float hacc = bias;
        for (int k = 0; k < 128; ++k) hacc += wrow[k] * p[k];
        if (tid < 8) out[b * 8 + tid] = hacc;
        else         out[1024 + b] = hacc;
    }
}

// ================================================================ host
extern "C" void kernel_launch(void* const* d_in, const int* in_sizes, int n_in,
                              void* d_out, int out_size, void* d_ws, size_t ws_size,
                              hipStream_t stream) {
    const float* x         = (const float*)d_in[0];
    const float* mask      = (const float*)d_in[1];
    const float* delta     = (const float*)d_in[2];
    const float* gru_w_ih  = (const float*)d_in[3];
    const float* gru_w_hh  = (const float*)d_in[4];
    const float* gru_b_ih  = (const float*)d_in[5];
    const float* gru_b_hh  = (const float*)d_in[6];
    const float* dm_w      = (const float*)d_in[7];
    const float* dm_b      = (const float*)d_in[8];
    const float* in_proj_w = (const float*)d_in[9];
    const float* in_proj_b = (const float*)d_in[10];
    const float* out_proj_w= (const float*)d_in[11];
    const float* out_proj_b= (const float*)d_in[12];
    const float* lin1_w    = (const float*)d_in[13];
    const float* lin1_b    = (const float*)d_in[14];
    const float* lin2_w    = (const float*)d_in[15];
    const float* lin2_b    = (const float*)d_in[16];
    const float* ln1_s     = (const float*)d_in[17];
    const float* ln1_bb    = (const float*)d_in[18];
    const float* ln2_s     = (const float*)d_in[19];
    const float* ln2_bb    = (const float*)d_in[20];
    const float* score_w   = (const float*)d_in[21];
    const float* score_b   = (const float*)d_in[22];
    const float* reg_w     = (const float*)d_in[23];
    const float* reg_b     = (const float*)d_in[24];
    const float* bin_w     = (const float*)d_in[25];
    const float* bin_b     = (const float*)d_in[26];
    const int*   window_id = (const int*)d_in[27];
    float* out = (float*)d_out;

    char* w8 = (char*)d_ws;
    float* z      = (float*)(w8 + 0);            // 16,777,216
    u16*   hsb    = (u16*)  (w8 + 25165824);     //  4,194,304
    u16*   wb_dm  = (u16*)  (w8 + 29360128);     //     16,384
    u16*   wb_ip  = (u16*)  (w8 + 29376512);     //    196,608
    u16*   wb_op  = (u16*)  (w8 + 29573120);     //     65,536
    u16*   wb_l1  = (u16*)  (w8 + 29638656);     //  1,048,576
    u16*   wb_l2  = (u16*)  (w8 + 30687232);     //  1,048,576
    float* tm     = (float*)(w8 + 31735808);     //    131,072
    float* xwt    = (float*)(w8 + 32063488);     // 25,165,824 (GRU: xwt2 fp32 | later: qkvb bf16)
    u16*   qkvb   = (u16*)  (w8 + 32063488);
    u16*   attnob = (u16*)  (w8 + 57229312);     //  8,388,608

    xw_kernel<<<2048, 192, 0, stream>>>(x, mask, delta, gru_w_ih, gru_b_ih, xwt);
    // combined: GRU v8 (blocks 0-15) + weight convert (16-595) + time mask (596-723)
    pre_kernel<<<724, 256, 0, stream>>>(gru_w_hh, gru_b_hh, xwt, hsb,
                                        dm_w, in_proj_w, out_proj_w, lin1_w, lin2_w,
                                        wb_dm, wb_ip, wb_op, wb_l1, wb_l2, mask, tm);

    dmqkv_kernel<<<256, 256, 0, stream>>>(hsb, wb_dm, dm_b, wb_ip, in_proj_b, z, qkvb);

    attn_mfma_kernel<<<BB * NHH, 256, 0, stream>>>(qkvb, tm, attnob);
    tailqkv_kernel<true><<<256, 256, 0, stream>>>(
        attnob, wb_op, out_proj_b, ln1_s, ln1_bb,
        wb_l1, lin1_b, wb_l2, lin2_b, ln2_s, ln2_bb,
        wb_ip + 49152, in_proj_b + 384, z, qkvb);

    attn_mfma_kernel<<<BB * NHH, 256, 0, stream>>>(qkvb, tm, attnob);
    tailqkv_kernel<false><<<256, 256, 0, stream>>>(
        attnob, wb_op + 16384, out_proj_b + 128, ln1_s + 128, ln1_bb + 128,
        wb_l1 + 262144, lin1_b + 2048, wb_l2 + 262144, lin2_b + 128,
        ln2_s + 128, ln2_bb + 128, nullptr, nullptr, z, nullptr);

    pool_all_kernel<<<BB, 256, 0, stream>>>(z, score_w, score_b, tm,
                                            reg_w, reg_b, bin_w, bin_b, window_id, out);
}

// Round 19
// 484.074 us; speedup vs baseline: 1.1046x; 1.1046x over previous
//
#include <hip/hip_runtime.h>

typedef __attribute__((ext_vector_type(8))) short short8;
typedef __attribute__((ext_vector_type(4))) float f32x4;
typedef unsigned short u16;

#define BB   128
#define SS   256
#define FIN  40
#define HH   64
#define DD   128
#define NHH  4
#define LL   2
#define NEGV (-1e9f)

__device__ __forceinline__ u16 f2b(float f) {
    unsigned u = __float_as_uint(f);
    return (u16)((u + 0x7FFFu + ((u >> 16) & 1u)) >> 16);
}
__device__ __forceinline__ float b2f(u16 u) {
    return __uint_as_float(((unsigned)u) << 16);
}

__device__ __forceinline__ void gl_lds16(const void* g, void* s) {
    __builtin_amdgcn_global_load_lds(
        (const __attribute__((address_space(1))) void*)g,
        (__attribute__((address_space(3))) void*)s, 16, 0, 0);
}

// ------------------------------------------------- xwt = concat(x,mask,delta) @ W_ih^T + b_ih
// TRANSPOSED output layout for the GRU: xwt[group 0..7][t 0..255][gatecol 0..191][rb 0..15]
__global__ __launch_bounds__(192) void xw_kernel(const float* __restrict__ x,
                                                 const float* __restrict__ mask,
                                                 const float* __restrict__ delta,
                                                 const float* __restrict__ w_ih,
                                                 const float* __restrict__ b_ih,
                                                 float* __restrict__ xwt) {
    __shared__ float inp[16][120];
    __shared__ float wl[192][21];
    int group = blockIdx.x >> 8;
    int t = blockIdx.x & 255;
    int tid = threadIdx.x;

    for (int idx = tid; idx < 16 * 120; idx += 192) {
        int r = idx / 120, k = idx % 120;
        size_t g = (size_t)(group * 16 + r) * 256 + t;
        float v;
        if (k < 40)      v = x[g * FIN + k];
        else if (k < 80) v = mask[g * FIN + (k - 40)];
        else             v = delta[g * FIN + (k - 80)];
        inp[r][k] = v;
    }

    float acc[16];
#pragma unroll
    for (int r = 0; r < 16; ++r) acc[r] = 0.f;

    for (int kt = 0; kt < 6; ++kt) {
        __syncthreads();
        for (int idx = tid; idx < 192 * 20; idx += 192) {
            int r = idx / 20, k = idx % 20;
            wl[r][k] = w_ih[(size_t)r * 120 + kt * 20 + k];
        }
        __syncthreads();
#pragma unroll
        for (int kk = 0; kk < 20; ++kk) {
            float w = wl[tid][kk];
            int kg = kt * 20 + kk;
#pragma unroll
            for (int r = 0; r < 16; ++r) acc[r] += w * inp[r][kg];
        }
    }
    float bias = b_ih[tid];
    float* o = xwt + ((size_t)(group * 256 + t) * 192 + tid) * 16;
#pragma unroll
    for (int r = 0; r < 16; r += 4) {
        float4 v = {acc[r] + bias, acc[r + 1] + bias, acc[r + 2] + bias, acc[r + 3] + bias};
        *(float4*)&o[r] = v;
    }
}

// ---------------------------------------------------------------- combined pre-kernel (R15/R17, frozen)
// blocks 0..7: GRU scan v6 (best measured: 162us; v7 LDS-staging and v8 wave-local both
// regressed — the ~1500cyc/step h-exchange serial chain is the structural floor).
// blocks 8..297: fp32->bf16 weight convert; blocks 298..361: time mask.
__device__ __forceinline__ float gru_gate(float xr, float xz, float xn,
                                          float ar, float az, float an, float hold) {
    float r  = 1.f / (1.f + __expf(-(xr + ar)));
    float zg = 1.f / (1.f + __expf(-(xz + az)));
    float nx = xn + r * an;
    float n  = 2.f / (1.f + __expf(-2.f * nx)) - 1.f;   // tanh
    return (1.f - zg) * n + zg * hold;
}

__global__ __launch_bounds__(512, 1) void pre_kernel(const float* __restrict__ w_hh,
                                                     const float* __restrict__ b_hh,
                                                     const float* __restrict__ xwt,
                                                     u16* __restrict__ hsb,
                                                     const float* __restrict__ dm_w,
                                                     const float* __restrict__ ip_w,
                                                     const float* __restrict__ op_w,
                                                     const float* __restrict__ l1_w,
                                                     const float* __restrict__ l2_w,
                                                     u16* __restrict__ o_dm, u16* __restrict__ o_ip,
                                                     u16* __restrict__ o_op, u16* __restrict__ o_l1,
                                                     u16* __restrict__ o_l2,
                                                     const float* __restrict__ mask,
                                                     float* __restrict__ tm) {
    __shared__ __align__(16) u16 hb[2][16 * 64];
    __shared__ __align__(16) u16 hstage[8][16 * 64];
    int blk = blockIdx.x;
    int tid = threadIdx.x;

    if (blk >= 8) {
        if (blk < 298) {
            int cb = blk - 8;
            const float* s; u16* d; int off;
            if      (cb < 2)   { s = dm_w; d = o_dm; off = cb; }
            else if (cb < 26)  { s = ip_w; d = o_ip; off = cb - 2; }
            else if (cb < 34)  { s = op_w; d = o_op; off = cb - 26; }
            else if (cb < 162) { s = l1_w; d = o_l1; off = cb - 34; }
            else               { s = l2_w; d = o_l2; off = cb - 162; }
            int i = (off * 512 + tid) * 8;
            float4 a = *(const float4*)&s[i];
            float4 b = *(const float4*)&s[i + 4];
            short8 o;
            o[0] = (short)f2b(a.x); o[1] = (short)f2b(a.y); o[2] = (short)f2b(a.z); o[3] = (short)f2b(a.w);
            o[4] = (short)f2b(b.x); o[5] = (short)f2b(b.y); o[6] = (short)f2b(b.z); o[7] = (short)f2b(b.w);
            *(short8*)&d[i] = o;
        } else {
            int row = (blk - 298) * 512 + tid;
            if (row < BB * SS) {
                const float* m = mask + (size_t)row * FIN;
                float s = 0.f;
                for (int f = 0; f < FIN; ++f) s += m[f];
                tm[row] = (s > 0.f) ? 1.f : 0.f;
            }
        }
        return;
    }

    int b0 = blk * 16;
    int w = tid >> 6, lane = tid & 63;
    int fr = lane & 15, hi = lane >> 4;
    int cw = w & 3;
    int jg = w >> 2;

    for (int idx = tid; idx < 1024; idx += 512) hb[0][idx] = 0;

    int c = cw * 16 + fr;
    float br_ = b_hh[c], bz_ = b_hh[64 + c], bn_ = b_hh[128 + c];

    short8 wfr[2], wfz[2], wfn[2];
#pragma unroll
    for (int ks = 0; ks < 2; ++ks) {
        int slot = ks * 4 + hi;
        const float* p0 = w_hh + (size_t)c * 64 + slot * 8;
        const float* p1 = w_hh + (size_t)(64 + c) * 64 + slot * 8;
        const float* p2 = w_hh + (size_t)(128 + c) * 64 + slot * 8;
#pragma unroll
        for (int q = 0; q < 8; ++q) {
            wfr[ks][q] = (short)f2b(p0[q]);
            wfz[ks][q] = (short)f2b(p1[q]);
            wfn[ks][q] = (short)f2b(p2[q]);
        }
    }

    const float* xg = xwt + (size_t)blk * (256 * 192 * 16);
    int lo = hi * 4 + jg * 2;

    float hrA = 0.f, hrB = 0.f;

    int woA = (lo + 0) * 64 + ((((c >> 3) ^ ((lo + 0) & 7))) << 3) + (c & 7);
    int woB = (lo + 1) * 64 + ((((c >> 3) ^ ((lo + 1) & 7))) << 3) + (c & 7);
    int soA = (lo + 0) * 64 + c;
    int soB = (lo + 1) * 64 + c;

    float2 pxr[4], pxz[4], pxn[4];
#pragma unroll
    for (int u = 0; u < 4; ++u) {
        pxr[u] = *(const float2*)&xg[((size_t)u * 192 + c) * 16 + lo];
        pxz[u] = *(const float2*)&xg[((size_t)u * 192 + 64 + c) * 16 + lo];
        pxn[u] = *(const float2*)&xg[((size_t)u * 192 + 128 + c) * 16 + lo];
    }
    __syncthreads();

    int cur = 0;
    auto step = [&](float2 xr2, float2 xz2, float2 xn2, int ts) {
        f32x4 ar = {br_, br_, br_, br_};
        f32x4 az = {bz_, bz_, bz_, bz_};
        f32x4 an = {bn_, bn_, bn_, bn_};
#pragma unroll
        for (int ks = 0; ks < 2; ++ks) {
            int soff = (((ks << 2) + hi) ^ (fr & 7)) << 3;
            short8 af = *(const short8*)&hb[cur][fr * 64 + soff];
            ar = __builtin_amdgcn_mfma_f32_16x16x32_bf16(af, wfr[ks], ar, 0, 0, 0);
            az = __builtin_amdgcn_mfma_f32_16x16x32_bf16(af, wfz[ks], az, 0, 0, 0);
            an = __builtin_amdgcn_mfma_f32_16x16x32_bf16(af, wfn[ks], an, 0, 0, 0);
        }
        float aR0, aR1, aZ0, aZ1, aN0, aN1;
        if (jg == 0) { aR0 = ar[0]; aR1 = ar[1]; aZ0 = az[0]; aZ1 = az[1]; aN0 = an[0]; aN1 = an[1]; }
        else         { aR0 = ar[2]; aR1 = ar[3]; aZ0 = az[2]; aZ1 = az[3]; aN0 = an[2]; aN1 = an[3]; }
        hrA = gru_gate(xr2.x, xz2.x, xn2.x, aR0, aZ0, aN0, hrA);
        hrB = gru_gate(xr2.y, xz2.y, xn2.y, aR1, aZ1, aN1, hrB);
        u16 v0 = f2b(hrA), v1 = f2b(hrB);
        int nxt = cur ^ 1;
        hb[nxt][woA] = v0; hb[nxt][woB] = v1;
        hstage[ts][soA] = v0; hstage[ts][soB] = v1;
        asm volatile("s_waitcnt lgkmcnt(0)\n\ts_barrier" ::: "memory");
        cur = nxt;
    };

    for (int t = 0; t < SS; t += 8) {
#pragma unroll
        for (int u = 0; u < 8; ++u) {
            int tp = t + u + 4; tp = (tp < SS) ? tp : (SS - 1);
            float2 nr = *(const float2*)&xg[((size_t)tp * 192 + c) * 16 + lo];
            float2 nz = *(const float2*)&xg[((size_t)tp * 192 + 64 + c) * 16 + lo];
            float2 nn = *(const float2*)&xg[((size_t)tp * 192 + 128 + c) * 16 + lo];
            step(pxr[u & 3], pxz[u & 3], pxn[u & 3], u);
            pxr[u & 3] = nr; pxz[u & 3] = nz; pxn[u & 3] = nn;
        }
#pragma unroll
        for (int f = 0; f < 2; ++f) {
            int idx = tid + f * 512;
            int c8 = idx & 7, pair = idx >> 3;
            int ts = pair >> 4, row = pair & 15;
            short8 v = *(const short8*)&hstage[ts][row * 64 + c8 * 8];
            *(short8*)&hsb[((size_t)(b0 + row) * SS + t + ts) * 64 + c8 * 8] = v;
        }
        asm volatile("s_waitcnt lgkmcnt(0)\n\ts_barrier" ::: "memory");
    }
}

// ---------------------------------------------------------------- fused dm + qkv(layer 0)
__global__ __launch_bounds__(256, 1) void dmqkv_kernel(const u16* __restrict__ hsb,
                                                       const u16* __restrict__ dmw,
                                                       const float* __restrict__ dmb,
                                                       const u16* __restrict__ ipw,
                                                       const float* __restrict__ ipb,
                                                       float* __restrict__ z,
                                                       u16* __restrict__ qkvb) {
    __shared__ __align__(16) u16 ZB[2][128 * 64];
    __shared__ __align__(16) u16 W1C[2][128 * 64];
    int bm = blockIdx.x;
    int tid = threadIdx.x;
    int w = tid >> 6, lane = tid & 63;
    int wrow = (w >> 1) * 64, wcol = (w & 1) * 64;
    int fr = lane & 15, hi = lane >> 4;
    int rl = lane >> 3, ssl = (lane & 7) ^ rl;
    int swz = fr & 7;

#pragma unroll
    for (int i = 0; i < 4; ++i) {
        int ch = w * 4 + i, row = ch * 8 + rl;
        gl_lds16(hsb + ((size_t)(bm * 128 + row)) * 64 + ssl * 8, &ZB[0][ch * 512]);
        gl_lds16(dmw + ((size_t)row) * 64 + ssl * 8, &W1C[0][ch * 512]);
    }
    __syncthreads();

    f32x4 acc[4][4];
#pragma unroll
    for (int m = 0; m < 4; ++m)
#pragma unroll
        for (int n = 0; n < 4; ++n) acc[m][n] = (f32x4){0.f, 0.f, 0.f, 0.f};
#pragma unroll
    for (int kk = 0; kk < 2; ++kk) {
        int soff = (((kk << 2) + hi) ^ swz) << 3;
        short8 a[4], b[4];
#pragma unroll
        for (int m = 0; m < 4; ++m)
            a[m] = *(const short8*)&ZB[0][(wrow + m * 16 + fr) * 64 + soff];
#pragma unroll
        for (int n = 0; n < 4; ++n)
            b[n] = *(const short8*)&W1C[0][(wcol + n * 16 + fr) * 64 + soff];
#pragma unroll
        for (int m = 0; m < 4; ++m)
#pragma unroll
            for (int n = 0; n < 4; ++n)
                acc[m][n] = __builtin_amdgcn_mfma_f32_16x16x32_bf16(a[m], b[n], acc[m][n], 0, 0, 0);
    }
    __syncthreads();

    float bv[4];
#pragma unroll
    for (int n = 0; n < 4; ++n) bv[n] = dmb[wcol + n * 16 + fr];
#pragma unroll
    for (int m = 0; m < 4; ++m)
#pragma unroll
        for (int j = 0; j < 4; ++j) {
            int lrow = wrow + m * 16 + hi * 4 + j;
            int row = bm * 128 + lrow;
#pragma unroll
            for (int n = 0; n < 4; ++n) {
                int col = wcol + n * 16 + fr;
                float o = acc[m][n][j] + bv[n];
                z[(size_t)row * 128 + col] = o;
                int e = col & 63;
                ZB[col >> 6][lrow * 64 + ((((e >> 3) ^ (lrow & 7))) << 3) + (e & 7)] = f2b(o);
            }
        }
    __syncthreads();

    for (int bn = 0; bn < 3; ++bn) {
#pragma unroll
        for (int hk = 0; hk < 2; ++hk)
#pragma unroll
            for (int i = 0; i < 4; ++i) {
                int ch = w * 4 + i, row = ch * 8 + rl;
                gl_lds16(ipw + ((size_t)(bn * 128 + row)) * 128 + hk * 64 + ssl * 8, &W1C[hk][ch * 512]);
            }
        __syncthreads();

        f32x4 aq[4][4];
#pragma unroll
        for (int m = 0; m < 4; ++m)
#pragma unroll
            for (int n = 0; n < 4; ++n) aq[m][n] = (f32x4){0.f, 0.f, 0.f, 0.f};
#pragma unroll
        for (int ks = 0; ks < 4; ++ks) {
            int hk = ks >> 1;
            int soff = ((((ks & 1) << 2) + hi) ^ swz) << 3;
            short8 a[4], b[4];
#pragma unroll
            for (int m = 0; m < 4; ++m)
                a[m] = *(const short8*)&ZB[hk][(wrow + m * 16 + fr) * 64 + soff];
#pragma unroll
            for (int n = 0; n < 4; ++n)
                b[n] = *(const short8*)&W1C[hk][(wcol + n * 16 + fr) * 64 + soff];
#pragma unroll
            for (int m = 0; m < 4; ++m)
#pragma unroll
                for (int n = 0; n < 4; ++n)
                    aq[m][n] = __builtin_amdgcn_mfma_f32_16x16x32_bf16(a[m], b[n], aq[m][n], 0, 0, 0);
        }
        float qb[4];
#pragma unroll
        for (int n = 0; n < 4; ++n) qb[n] = ipb[bn * 128 + wcol + n * 16 + fr];
#pragma unroll
        for (int m = 0; m < 4; ++m)
#pragma unroll
            for (int j = 0; j < 4; ++j) {
                int row = bm * 128 + wrow + m * 16 + hi * 4 + j;
#pragma unroll
                for (int n = 0; n < 4; ++n)
                    qkvb[(size_t)row * 384 + bn * 128 + wcol + n * 16 + fr] = f2b(aq[m][n][j] + qb[n]);
            }
        __syncthreads();
    }
}

// ---------------------------------------------------------------- fused layer tail (+ next-layer qkv)
template <bool DO_QKV>
__global__ __launch_bounds__(256, 1) void tailqkv_kernel(const u16* __restrict__ attnob,
                                                         const u16* __restrict__ opw,
                                                         const float* __restrict__ opb,
                                                         const float* __restrict__ ln1s,
                                                         const float* __restrict__ ln1b,
                                                         const u16* __restrict__ w1,
                                                         const float* __restrict__ b1,
                                                         const u16* __restrict__ w2,
                                                         const float* __restrict__ b2,
                                                         const float* __restrict__ lns,
                                                         const float* __restrict__ lnb,
                                                         const u16* __restrict__ ipw,
                                                         const float* __restrict__ ipb,
                                                         float* __restrict__ z,
                                                         u16* __restrict__ qkvb) {
    __shared__ __align__(16) u16 ZB[2][128 * 64];
    __shared__ __align__(16) u16 W1C[2][128 * 64];
    __shared__ __align__(16) u16 W2C[2][128 * 64];
    __shared__ __align__(16) u16 A1[2][128 * 64];
    __shared__ float lred[2][2][128];
    int bm = blockIdx.x;
    int tid = threadIdx.x;
    int w = tid >> 6, lane = tid & 63;
    int wrow = (w >> 1) * 64, wcol = (w & 1) * 64;
    int fr = lane & 15, hi = lane >> 4;
    int rl = lane >> 3, ssl = (lane & 7) ^ rl;
    int swz = fr & 7;
    int xh = wrow >> 6;

#pragma unroll
    for (int hk = 0; hk < 2; ++hk)
#pragma unroll
        for (int i = 0; i < 4; ++i) {
            int ch = w * 4 + i, row = ch * 8 + rl;
            gl_lds16(attnob + ((size_t)(bm * 128 + row)) * 128 + hk * 64 + ssl * 8, &ZB[hk][ch * 512]);
            gl_lds16(opw + ((size_t)row) * 128 + hk * 64 + ssl * 8, &W1C[hk][ch * 512]);
        }
    __syncthreads();

    {
        f32x4 acc1[4][4];
#pragma unroll
        for (int m = 0; m < 4; ++m)
#pragma unroll
            for (int n = 0; n < 4; ++n) acc1[m][n] = (f32x4){0.f, 0.f, 0.f, 0.f};
#pragma unroll
        for (int ks = 0; ks < 4; ++ks) {
            int hk = ks >> 1;
            int soff = ((((ks & 1) << 2) + hi) ^ swz) << 3;
            short8 a[4], b[4];
#pragma unroll
            for (int m = 0; m < 4; ++m)
                a[m] = *(const short8*)&ZB[hk][(wrow + m * 16 + fr) * 64 + soff];
#pragma unroll
            for (int n = 0; n < 4; ++n)
                b[n] = *(const short8*)&W1C[hk][(wcol + n * 16 + fr) * 64 + soff];
#pragma unroll
            for (int m = 0; m < 4; ++m)
#pragma unroll
                for (int n = 0; n < 4; ++n)
                    acc1[m][n] = __builtin_amdgcn_mfma_f32_16x16x32_bf16(a[m], b[n], acc1[m][n], 0, 0, 0);
        }

        float bv[4];
#pragma unroll
        for (int n = 0; n < 4; ++n) bv[n] = opb[wcol + n * 16 + fr];
        float v[4][4][4];
#pragma unroll
        for (int m = 0; m < 4; ++m)
#pragma unroll
            for (int j = 0; j < 4; ++j) {
                int row = bm * 128 + wrow + m * 16 + hi * 4 + j;
#pragma unroll
                for (int n = 0; n < 4; ++n)
                    v[m][n][j] = acc1[m][n][j] + bv[n] + z[(size_t)row * 128 + wcol + n * 16 + fr];
            }
#pragma unroll
        for (int m = 0; m < 4; ++m)
#pragma unroll
            for (int j = 0; j < 4; ++j) {
                float s = v[m][0][j] + v[m][1][j] + v[m][2][j] + v[m][3][j];
                float q = v[m][0][j]*v[m][0][j] + v[m][1][j]*v[m][1][j]
                        + v[m][2][j]*v[m][2][j] + v[m][3][j]*v[m][3][j];
#pragma unroll
                for (int off = 1; off <= 8; off <<= 1) {
                    s += __shfl_xor(s, off);
                    q += __shfl_xor(q, off);
                }
                if (fr == 0) {
                    int lrow = wrow + m * 16 + hi * 4 + j;
                    lred[0][w & 1][lrow] = s;
                    lred[1][w & 1][lrow] = q;
                }
            }
        __syncthreads();
        float sv[4], bb[4];
#pragma unroll
        for (int n = 0; n < 4; ++n) {
            sv[n] = ln1s[wcol + n * 16 + fr];
            bb[n] = ln1b[wcol + n * 16 + fr];
        }
#pragma unroll
        for (int m = 0; m < 4; ++m)
#pragma unroll
            for (int j = 0; j < 4; ++j) {
                int lrow = wrow + m * 16 + hi * 4 + j;
                float mean = (lred[0][0][lrow] + lred[0][1][lrow]) * (1.f / 128.f);
                float msq  = (lred[1][0][lrow] + lred[1][1][lrow]) * (1.f / 128.f);
                float rstd = rsqrtf(msq - mean * mean + 1e-5f);
                int row = bm * 128 + lrow;
#pragma unroll
                for (int n = 0; n < 4; ++n) {
                    int col = wcol + n * 16 + fr;
                    float o = (v[m][n][j] - mean) * rstd * sv[n] + bb[n];
                    z[(size_t)row * 128 + col] = o;
                    int e = col & 63;
                    ZB[col >> 6][lrow * 64 + ((((e >> 3) ^ (lrow & 7))) << 3) + (e & 7)] = f2b(o);
                }
            }
    }
    __syncthreads();

    f32x4 acc2[4][4];
#pragma unroll
    for (int m = 0; m < 4; ++m)
#pragma unroll
        for (int n = 0; n < 4; ++n) acc2[m][n] = (f32x4){0.f, 0.f, 0.f, 0.f};

    for (int ci = 0; ci < 16; ++ci) {
#pragma unroll
        for (int hk = 0; hk < 2; ++hk)
#pragma unroll
            for (int i = 0; i < 4; ++i) {
                int ch = w * 4 + i, row = ch * 8 + rl;
                gl_lds16(w1 + ((size_t)(ci * 128 + row)) * 128 + hk * 64 + ssl * 8, &W1C[hk][ch * 512]);
                gl_lds16(w2 + ((size_t)row) * 2048 + ci * 128 + hk * 64 + ssl * 8, &W2C[hk][ch * 512]);
            }
        __syncthreads();

        f32x4 acc1[4][4];
#pragma unroll
        for (int m = 0; m < 4; ++m)
#pragma unroll
            for (int n = 0; n < 4; ++n) acc1[m][n] = (f32x4){0.f, 0.f, 0.f, 0.f};
#pragma unroll
        for (int ks = 0; ks < 4; ++ks) {
            int hk = ks >> 1;
            int soff = ((((ks & 1) << 2) + hi) ^ swz) << 3;
            short8 a[4], b[4];
#pragma unroll
            for (int m = 0; m < 4; ++m)
                a[m] = *(const short8*)&W1C[hk][(wrow + m * 16 + fr) * 64 + soff];
#pragma unroll
            for (int n = 0; n < 4; ++n)
                b[n] = *(const short8*)&ZB[hk][(wcol + n * 16 + fr) * 64 + soff];
#pragma unroll
            for (int m = 0; m < 4; ++m)
#pragma unroll
                for (int n = 0; n < 4; ++n)
                    acc1[m][n] = __builtin_amdgcn_mfma_f32_16x16x32_bf16(a[m], b[n], acc1[m][n], 0, 0, 0);
        }
#pragma unroll
        for (int m = 0; m < 4; ++m) {
            int x0 = wrow + m * 16 + hi * 4;
            float4 bb = *(const float4*)&b1[ci * 128 + x0];
            int slot = (x0 & 63) >> 3;
            int wadd = x0 & 7;
#pragma unroll
            for (int n = 0; n < 4; ++n) {
                int r = wcol + n * 16 + fr;
                float v0 = fmaxf(acc1[m][n][0] + bb.x, 0.f);
                float v1 = fmaxf(acc1[m][n][1] + bb.y, 0.f);
                float v2 = fmaxf(acc1[m][n][2] + bb.z, 0.f);
                float v3 = fmaxf(acc1[m][n][3] + bb.w, 0.f);
                uint2 pk;
                pk.x = (unsigned)f2b(v0) | ((unsigned)f2b(v1) << 16);
                pk.y = (unsigned)f2b(v2) | ((unsigned)f2b(v3) << 16);
                *(uint2*)&A1[xh][r * 64 + ((slot ^ (r & 7)) << 3) + wadd] = pk;
            }
        }
        __syncthreads();

#pragma unroll
        for (int ks = 0; ks < 4; ++ks) {
            int hk = ks >> 1;
            int soff = ((((ks & 1) << 2) + hi) ^ swz) << 3;
            short8 a[4], b[4];
#pragma unroll
            for (int m = 0; m < 4; ++m)
                a[m] = *(const short8*)&W2C[hk][(wrow + m * 16 + fr) * 64 + soff];
#pragma unroll
            for (int n = 0; n < 4; ++n)
                b[n] = *(const short8*)&A1[hk][(wcol + n * 16 + fr) * 64 + soff];
#pragma unroll
            for (int m = 0; m < 4; ++m)
#pragma unroll
                for (int n = 0; n < 4; ++n)
                    acc2[m][n] = __builtin_amdgcn_mfma_f32_16x16x32_bf16(a[m], b[n], acc2[m][n], 0, 0, 0);
        }
        __syncthreads();
    }

    float vv[4][4][4];
#pragma unroll
    for (int m = 0; m < 4; ++m) {
        int x0 = wrow + m * 16 + hi * 4;
        float4 bb = *(const float4*)&b2[x0];
#pragma unroll
        for (int n = 0; n < 4; ++n) {
            int y = wcol + n * 16 + fr;
            float4 zo = *(const float4*)&z[((size_t)(bm * 128 + y)) * 128 + x0];
            vv[m][n][0] = acc2[m][n][0] + bb.x + zo.x;
            vv[m][n][1] = acc2[m][n][1] + bb.y + zo.y;
            vv[m][n][2] = acc2[m][n][2] + bb.z + zo.z;
            vv[m][n][3] = acc2[m][n][3] + bb.w + zo.w;
        }
    }
#pragma unroll
    for (int n = 0; n < 4; ++n) {
        float s = 0.f, q = 0.f;
#pragma unroll
        for (int m = 0; m < 4; ++m)
#pragma unroll
            for (int j = 0; j < 4; ++j) { float v = vv[m][n][j]; s += v; q += v * v; }
        s += __shfl_xor(s, 16); s += __shfl_xor(s, 32);
        q += __shfl_xor(q, 16); q += __shfl_xor(q, 32);
        if (hi == 0) {
            int y = wcol + n * 16 + fr;
            lred[0][xh][y] = s;
            lred[1][xh][y] = q;
        }
    }
    __syncthreads();
#pragma unroll
    for (int n = 0; n < 4; ++n) {
        int y = wcol + n * 16 + fr;
        float mean = (lred[0][0][y] + lred[0][1][y]) * (1.f / 128.f);
        float msq  = (lred[1][0][y] + lred[1][1][y]) * (1.f / 128.f);
        float rstd = rsqrtf(msq - mean * mean + 1e-5f);
#pragma unroll
        for (int m = 0; m < 4; ++m) {
            int x0 = wrow + m * 16 + hi * 4;
            float4 sv = *(const float4*)&lns[x0];
            float4 bv = *(const float4*)&lnb[x0];
            float o0 = (vv[m][n][0] - mean) * rstd * sv.x + bv.x;
            float o1 = (vv[m][n][1] - mean) * rstd * sv.y + bv.y;
            float o2 = (vv[m][n][2] - mean) * rstd * sv.z + bv.z;
            float o3 = (vv[m][n][3] - mean) * rstd * sv.w + bv.w;
            size_t zoff = ((size_t)(bm * 128 + y)) * 128 + x0;
            *(float4*)&z[zoff] = (float4){o0, o1, o2, o3};
            if (DO_QKV) {
#pragma unroll
                for (int j = 0; j < 4; ++j) {
                    int col = x0 + j;
                    int e = col & 63;
                    float ov = (j == 0) ? o0 : (j == 1) ? o1 : (j == 2) ? o2 : o3;
                    ZB[col >> 6][y * 64 + ((((e >> 3) ^ (y & 7))) << 3) + (e & 7)] = f2b(ov);
                }
            }
        }
    }

    if (DO_QKV) {
        __syncthreads();
        for (int bn = 0; bn < 3; ++bn) {
#pragma unroll
            for (int hk = 0; hk < 2; ++hk)
#pragma unroll
                for (int i = 0; i < 4; ++i) {
                    int ch = w * 4 + i, row = ch * 8 + rl;
                    gl_lds16(ipw + ((size_t)(bn * 128 + row)) * 128 + hk * 64 + ssl * 8, &W1C[hk][ch * 512]);
                }
            __syncthreads();

            f32x4 aq[4][4];
#pragma unroll
            for (int m = 0; m < 4; ++m)
#pragma unroll
                for (int n = 0; n < 4; ++n) aq[m][n] = (f32x4){0.f, 0.f, 0.f, 0.f};
#pragma unroll
            for (int ks = 0; ks < 4; ++ks) {
                int hk = ks >> 1;
                int soff = ((((ks & 1) << 2) + hi) ^ swz) << 3;
                short8 a[4], b[4];
#pragma unroll
                for (int m = 0; m < 4; ++m)
                    a[m] = *(const short8*)&ZB[hk][(wrow + m * 16 + fr) * 64 + soff];
#pragma unroll
                for (int n = 0; n < 4; ++n)
                    b[n] = *(const short8*)&W1C[hk][(wcol + n * 16 + fr) * 64 + soff];
#pragma unroll
                for (int m = 0; m < 4; ++m)
#pragma unroll
                    for (int n = 0; n < 4; ++n)
                        aq[m][n] = __builtin_amdgcn_mfma_f32_16x16x32_bf16(a[m], b[n], aq[m][n], 0, 0, 0);
            }
            float qb[4];
#pragma unroll
            for (int n = 0; n < 4; ++n) qb[n] = ipb[bn * 128 + wcol + n * 16 + fr];
#pragma unroll
            for (int m = 0; m < 4; ++m)
#pragma unroll
                for (int j = 0; j < 4; ++j) {
                    int row = bm * 128 + wrow + m * 16 + hi * 4 + j;
#pragma unroll
                    for (int n = 0; n < 4; ++n)
                        qkvb[(size_t)row * 384 + bn * 128 + wcol + n * 16 + fr] = f2b(aq[m][n][j] + qb[n]);
                }
            __syncthreads();
        }
    }
}

// ---------------------------------------------------------------- MFMA attention
__global__ __launch_bounds__(256) void attn_mfma_kernel(const u16* __restrict__ qkv,
                                                        const float* __restrict__ tm,
                                                        u16* __restrict__ attno) {
    __shared__ __align__(16) u16 Kl[256 * 40];
    __shared__ __align__(16) u16 Vt[32 * 264];
    __shared__ __align__(16) u16 Pl[4][64 * 72];
    __shared__ float tmb[256];
    int bh = blockIdx.x;
    int b = bh >> 2, hd = bh & 3;
    int tid = threadIdx.x;
    int w = tid >> 6, lane = tid & 63;
    int fr = lane & 15, hi = lane >> 4;
    const u16* base = qkv + (size_t)b * SS * 384 + hd * 32;

    for (int idx = tid; idx < 1024; idx += 256) {
        int r = idx >> 2, s = idx & 3;
        short8 v = *(const short8*)(base + (size_t)r * 384 + 128 + s * 8);
        *(short8*)&Kl[r * 40 + s * 8] = v;
    }
    for (int idx = tid; idx < 1024; idx += 256) {
        int r = idx >> 2, s = idx & 3;
        short8 v = *(const short8*)(base + (size_t)r * 384 + 256 + s * 8);
#pragma unroll
        for (int q = 0; q < 8; ++q) Vt[(s * 8 + q) * 264 + r] = (u16)v[q];
    }
    tmb[tid] = (tm[b * SS + tid] > 0.f) ? 0.f : NEGV;

    int q0 = w * 64;
    short8 qf[4];
#pragma unroll
    for (int m = 0; m < 4; ++m)
        qf[m] = *(const short8*)(base + (size_t)(q0 + m * 16 + fr) * 384 + hi * 8);
    __syncthreads();

    const float scale = 0.17677669529663687f;
    f32x4 accO[4][2];
#pragma unroll
    for (int m = 0; m < 4; ++m) {
        accO[m][0] = (f32x4){0.f, 0.f, 0.f, 0.f};
        accO[m][1] = (f32x4){0.f, 0.f, 0.f, 0.f};
    }
    float den[4][4];
#pragma unroll
    for (int m = 0; m < 4; ++m)
#pragma unroll
        for (int j = 0; j < 4; ++j) den[m][j] = 0.f;

    u16* pw = &Pl[w][0];

    for (int kt = 0; kt < 4; ++kt) {
        f32x4 accS[4][4];
#pragma unroll
        for (int m = 0; m < 4; ++m)
#pragma unroll
            for (int n = 0; n < 4; ++n) accS[m][n] = (f32x4){0.f, 0.f, 0.f, 0.f};
        short8 kf[4];
#pragma unroll
        for (int n = 0; n < 4; ++n)
            kf[n] = *(const short8*)&Kl[(kt * 64 + n * 16 + fr) * 40 + hi * 8];
#pragma unroll
        for (int m = 0; m < 4; ++m)
#pragma unroll
            for (int n = 0; n < 4; ++n)
                accS[m][n] = __builtin_amdgcn_mfma_f32_16x16x32_bf16(qf[m], kf[n], accS[m][n], 0, 0, 0);

        float bias[4];
#pragma unroll
        for (int n = 0; n < 4; ++n) bias[n] = tmb[kt * 64 + n * 16 + fr];

#pragma unroll
        for (int m = 0; m < 4; ++m) {
            float rs0 = 0.f, rs1 = 0.f, rs2 = 0.f, rs3 = 0.f;
#pragma unroll
            for (int n = 0; n < 4; ++n) {
                float p0 = __expf(accS[m][n][0] * scale + bias[n]);
                float p1 = __expf(accS[m][n][1] * scale + bias[n]);
                float p2 = __expf(accS[m][n][2] * scale + bias[n]);
                float p3 = __expf(accS[m][n][3] * scale + bias[n]);
                rs0 += p0; rs1 += p1; rs2 += p2; rs3 += p3;
                int cb = n * 16 + fr;
                pw[(m * 16 + hi * 4 + 0) * 72 + cb] = f2b(p0);
                pw[(m * 16 + hi * 4 + 1) * 72 + cb] = f2b(p1);
                pw[(m * 16 + hi * 4 + 2) * 72 + cb] = f2b(p2);
                pw[(m * 16 + hi * 4 + 3) * 72 + cb] = f2b(p3);
            }
#pragma unroll
            for (int off = 1; off <= 8; off <<= 1) {
                rs0 += __shfl_xor(rs0, off);
                rs1 += __shfl_xor(rs1, off);
                rs2 += __shfl_xor(rs2, off);
                rs3 += __shfl_xor(rs3, off);
            }
            den[m][0] += rs0; den[m][1] += rs1; den[m][2] += rs2; den[m][3] += rs3;
        }
        asm volatile("s_waitcnt lgkmcnt(0)" ::: "memory");

#pragma unroll
        for (int ks = 0; ks < 2; ++ks) {
            short8 pf[4], vf[2];
#pragma unroll
            for (int m = 0; m < 4; ++m)
                pf[m] = *(const short8*)&pw[(m * 16 + fr) * 72 + ks * 32 + hi * 8];
#pragma unroll
            for (int nd = 0; nd < 2; ++nd)
                vf[nd] = *(const short8*)&Vt[(nd * 16 + fr) * 264 + kt * 64 + ks * 32 + hi * 8];
#pragma unroll
            for (int m = 0; m < 4; ++m)
#pragma unroll
                for (int nd = 0; nd < 2; ++nd)
                    accO[m][nd] = __builtin_amdgcn_mfma_f32_16x16x32_bf16(pf[m], vf[nd], accO[m][nd], 0, 0, 0);
        }
    }

    u16* orow = attno + (size_t)(b * SS + q0) * DD + hd * 32;
#pragma unroll
    for (int m = 0; m < 4; ++m)
#pragma unroll
        for (int j = 0; j < 4; ++j) {
            float inv = 1.f / den[m][j];
            int qr = m * 16 + hi * 4 + j;
            orow[(size_t)qr * DD + fr]      = f2b(accO[m][0][j] * inv);
            orow[(size_t)qr * DD + 16 + fr] = f2b(accO[m][1][j] * inv);
        }
}

// ---------------------------------------------------------------- fused score + softmax-pool + routed heads
__global__ __launch_bounds__(256) void pool_all_kernel(const float* __restrict__ z,
                                                       const float* __restrict__ score_w,
                                                       const float* __restrict__ score_b,
                                                       const float* __restrict__ tm,
                                                       const float* __restrict__ reg_w,
                                                       const float* __restrict__ reg_b,
                                                       const float* __restrict__ bin_w,
                                                       const float* __restrict__ bin_b,
                                                       const int* __restrict__ wid,
                                                       float* __restrict__ out) {
    int b = blockIdx.x;
    int tid = threadIdx.x;
    __shared__ float sw[128];
    __shared__ float al[SS];
    __shared__ float red[8];
    __shared__ float pp[2][128];
    __shared__ float p[128];

    if (tid < 128) sw[tid] = score_w[tid];
    __syncthreads();

    const float* zr = z + ((size_t)b * SS + tid) * DD;
    float acc = 0.f;
#pragma unroll
    for (int j = 0; j < 128; j += 4) {
        float4 a = *(const float4*)&zr[j];
        float4 wv = *(const float4*)&sw[j];
        acc += a.x * wv.x + a.y * wv.y + a.z * wv.z + a.w * wv.w;
    }
    float sc = acc + score_b[0];
    sc = (tm[b * SS + tid] > 0.f) ? sc : NEGV;

    float m = sc;
#pragma unroll
    for (int off = 32; off; off >>= 1) m = fmaxf(m, __shfl_xor(m, off));
    if ((tid & 63) == 0) red[tid >> 6] = m;
    __syncthreads();
    m = fmaxf(fmaxf(red[0], red[1]), fmaxf(red[2], red[3]));
    float e = __expf(sc - m);
    float ssum = e;
#pragma unroll
    for (int off = 32; off; off >>= 1) ssum += __shfl_xor(ssum, off);
    if ((tid & 63) == 0) red[4 + (tid >> 6)] = ssum;
    __syncthreads();
    ssum = red[4] + red[5] + red[6] + red[7];
    al[tid] = e / ssum;
    __syncthreads();

    int d = tid & 127, half = tid >> 7;
    float pa = 0.f;
    for (int t = half; t < SS; t += 2) pa += al[t] * z[((size_t)b * SS + t) * DD + d];
    pp[half][d] = pa;
    __syncthreads();
    if (tid < 128) p[tid] = pp[0][tid] + pp[1][tid];
    __syncthreads();

    if (tid < 9) {
        int wi = wid[b];
        const float* wrow;
        float bias;
        if (tid < 8) { wrow = reg_w + ((size_t)wi * 8 + tid) * 128; bias = reg_b[wi * 8 + tid]; }
        else         { wrow = bin_w + (size_t)wi * 128;             bias = bin_b[wi]; }
        float hacc = bias;
        for (int k = 0; k < 128; ++k) hacc += wrow[k] * p[k];
        if (tid < 8) out[b * 8 + tid] = hacc;
        else         out[1024 + b] = hacc;
    }
}

// ================================================================ host
extern "C" void kernel_launch(void* const* d_in, const int* in_sizes, int n_in,
                              void* d_out, int out_size, void* d_ws, size_t ws_size,
                              hipStream_t stream) {
    const float* x         = (const float*)d_in[0];
    const float* mask      = (const float*)d_in[1];
    const float* delta     = (const float*)d_in[2];
    const float* gru_w_ih  = (const float*)d_in[3];
    const float* gru_w_hh  = (const float*)d_in[4];
    const float* gru_b_ih  = (const float*)d_in[5];
    const float* gru_b_hh  = (const float*)d_in[6];
    const float* dm_w      = (const float*)d_in[7];
    const float* dm_b      = (const float*)d_in[8];
    const float* in_proj_w = (const float*)d_in[9];
    const float* in_proj_b = (const float*)d_in[10];
    const float* out_proj_w= (const float*)d_in[11];
    const float* out_proj_b= (const float*)d_in[12];
    const float* lin1_w    = (const float*)d_in[13];
    const float* lin1_b    = (const float*)d_in[14];
    const float* lin2_w    = (const float*)d_in[15];
    const float* lin2_b    = (const float*)d_in[16];
    const float* ln1_s     = (const float*)d_in[17];
    const float* ln1_bb    = (const float*)d_in[18];
    const float* ln2_s     = (const float*)d_in[19];
    const float* ln2_bb    = (const float*)d_in[20];
    const float* score_w   = (const float*)d_in[21];
    const float* score_b   = (const float*)d_in[22];
    const float* reg_w     = (const float*)d_in[23];
    const float* reg_b     = (const float*)d_in[24];
    const float* bin_w     = (const float*)d_in[25];
    const float* bin_b     = (const float*)d_in[26];
    const int*   window_id = (const int*)d_in[27];
    float* out = (float*)d_out;

    char* w8 = (char*)d_ws;
    float* z      = (float*)(w8 + 0);            // 16,777,216
    u16*   hsb    = (u16*)  (w8 + 25165824);     //  4,194,304
    u16*   wb_dm  = (u16*)  (w8 + 29360128);     //     16,384
    u16*   wb_ip  = (u16*)  (w8 + 29376512);     //    196,608
    u16*   wb_op  = (u16*)  (w8 + 29573120);     //     65,536
    u16*   wb_l1  = (u16*)  (w8 + 29638656);     //  1,048,576
    u16*   wb_l2  = (u16*)  (w8 + 30687232);     //  1,048,576
    float* tm     = (float*)(w8 + 31735808);     //    131,072
    float* xwt    = (float*)(w8 + 32063488);     // 25,165,824 (GRU: xwt fp32 | later: qkvb bf16)
    u16*   qkvb   = (u16*)  (w8 + 32063488);
    u16*   attnob = (u16*)  (w8 + 57229312);     //  8,388,608

    xw_kernel<<<2048, 192, 0, stream>>>(x, mask, delta, gru_w_ih, gru_b_ih, xwt);
    pre_kernel<<<362, 512, 0, stream>>>(gru_w_hh, gru_b_hh, xwt, hsb,
                                        dm_w, in_proj_w, out_proj_w, lin1_w, lin2_w,
                                        wb_dm, wb_ip, wb_op, wb_l1, wb_l2, mask, tm);

    // fused dm + qkv(layer0)
    dmqkv_kernel<<<256, 256, 0, stream>>>(hsb, wb_dm, dm_b, wb_ip, in_proj_b, z, qkvb);

    // layer 0
    attn_mfma_kernel<<<BB * NHH, 256, 0, stream>>>(qkvb, tm, attnob);
    tailqkv_kernel<true><<<256, 256, 0, stream>>>(
        attnob, wb_op, out_proj_b, ln1_s, ln1_bb,
        wb_l1, lin1_b, wb_l2, lin2_b, ln2_s, ln2_bb,
        wb_ip + 49152, in_proj_b + 384, z, qkvb);

    // layer 1
    attn_mfma_kernel<<<BB * NHH, 256, 0, stream>>>(qkvb, tm, attnob);
    tailqkv_kernel<false><<<256, 256, 0, stream>>>(
        attnob, wb_op + 16384, out_proj_b + 128, ln1_s + 128, ln1_bb + 128,
        wb_l1 + 262144, lin1_b + 2048, wb_l2 + 262144, lin2_b + 128,
        ln2_s + 128, ln2_bb + 128, nullptr, nullptr, z, nullptr);

    pool_all_kernel<<<BB, 256, 0, stream>>>(z, score_w, score_b, tm,
                                            reg_w, reg_b, bin_w, bin_b, window_id, out);
}